// Round 14
// baseline (124.742 us; speedup 1.0000x reference)
//
#include <hip/hip_runtime.h>

#define B_ 8
#define N_ 1024
#define DIM_ 512
#define H_ 8
#define D_ 64
#define PD_ 50
#define PBROWS 256

typedef __attribute__((ext_vector_type(4))) float f32x4;
typedef __attribute__((ext_vector_type(8))) __bf16 bf16x8;

__device__ __forceinline__ unsigned short f2bf(float f) {
    unsigned int u = __float_as_uint(f);
    u += 0x7FFFu + ((u >> 16) & 1u);   // round-to-nearest-even
    return (unsigned short)(u >> 16);
}

// ---------------- fp32 -> bf16 cast: x, W_kv, W_out in ONE launch ----------------
__global__ __launch_bounds__(256) void cast_all(const float* __restrict__ x,
                                                const float* __restrict__ wkv,
                                                const float* __restrict__ wout,
                                                unsigned short* __restrict__ xb,
                                                unsigned short* __restrict__ wkvb,
                                                unsigned short* __restrict__ woutb) {
    const int bid = blockIdx.x;
    const float* src;
    unsigned short* dst;
    int idx;
    if (bid < 4096)      { src = x;    dst = xb;    idx = bid; }
    else if (bid < 4608) { src = wkv;  dst = wkvb;  idx = bid - 4096; }
    else                 { src = wout; dst = woutb; idx = bid - 4608; }
    int i = idx * 256 + threadIdx.x;
    float4 v = reinterpret_cast<const float4*>(src)[i];
    ushort4 o;
    o.x = f2bf(v.x); o.y = f2bf(v.y); o.z = f2bf(v.z); o.w = f2bf(v.w);
    reinterpret_cast<ushort4*>(dst)[i] = o;
}

// ---------------- pos_bias: LDS-staged, coalesced float4 global loads ----------------
__global__ __launch_bounds__(256) void pos_bias_kernel(const float* __restrict__ pos,
                                                       const float* __restrict__ w_pos,
                                                       float* __restrict__ pb) {
    __shared__ float buf[PBROWS * PD_];   // 51.2 KB
    const int t = threadIdx.x;
    const size_t base = (size_t)blockIdx.x * (PBROWS * PD_);
    const float4* src = reinterpret_cast<const float4*>(pos + base);
    float4* dst = reinterpret_cast<float4*>(buf);
#pragma unroll 4
    for (int i = t; i < PBROWS * PD_ / 4; i += 256)
        dst[i] = src[i];
    __syncthreads();
    float acc = 0.f;
    const float* row = buf + t * PD_;
#pragma unroll
    for (int p = 0; p < PD_; p++) acc += row[p] * w_pos[p];
    pb[(size_t)blockIdx.x * PBROWS + t] = acc;
}

// ---------------- kv = x @ W_kv^T, 128x64 tile, BK=64, scatter k->kb, v->vt ----------------
__global__ __launch_bounds__(256) void kv_gemm(const unsigned short* __restrict__ xb,
                                               const unsigned short* __restrict__ wb,
                                               unsigned short* __restrict__ kb,
                                               unsigned short* __restrict__ vt) {
    __shared__ __align__(16) unsigned short As[128][72];   // +8 pad
    __shared__ __align__(16) unsigned short Bs[64][72];
    const int m0 = blockIdx.x * 128;
    const int n0 = blockIdx.y * 64;
    const int t = threadIdx.x;
    const int w = t >> 6, l = t & 63;
    const int wr = (w >> 1) * 64, wc = (w & 1) * 32;
    const int lr = l & 15, lg = l >> 4;
    const int ar = t >> 1, ac = (t & 1) * 32;          // A: 4 x bf16x8 per thread
    const int br = t >> 2, bc = (t & 3) * 16;          // B: 2 x bf16x8 per thread

    f32x4 acc[4][2] = {};

    for (int k0 = 0; k0 < DIM_; k0 += 64) {
        __syncthreads();
#pragma unroll
        for (int u = 0; u < 4; u++)
            *reinterpret_cast<bf16x8*>(&As[ar][ac + u * 8]) =
                *reinterpret_cast<const bf16x8*>(&xb[(size_t)(m0 + ar) * DIM_ + k0 + ac + u * 8]);
#pragma unroll
        for (int u = 0; u < 2; u++)
            *reinterpret_cast<bf16x8*>(&Bs[br][bc + u * 8]) =
                *reinterpret_cast<const bf16x8*>(&wb[(size_t)(n0 + br) * DIM_ + k0 + bc + u * 8]);
        __syncthreads();
#pragma unroll
        for (int kh = 0; kh < 2; kh++) {
            bf16x8 b0 = *reinterpret_cast<const bf16x8*>(&Bs[wc + lr][kh * 32 + lg * 8]);
            bf16x8 b1 = *reinterpret_cast<const bf16x8*>(&Bs[wc + 16 + lr][kh * 32 + lg * 8]);
#pragma unroll
            for (int fm = 0; fm < 4; fm++) {
                bf16x8 a = *reinterpret_cast<const bf16x8*>(&As[wr + fm * 16 + lr][kh * 32 + lg * 8]);
                acc[fm][0] = __builtin_amdgcn_mfma_f32_16x16x32_bf16(a, b0, acc[fm][0], 0, 0, 0);
                acc[fm][1] = __builtin_amdgcn_mfma_f32_16x16x32_bf16(a, b1, acc[fm][1], 0, 0, 0);
            }
        }
    }

#pragma unroll
    for (int fm = 0; fm < 4; fm++)
#pragma unroll
        for (int fn = 0; fn < 2; fn++) {
            int gn = n0 + wc + fn * 16 + lr;
#pragma unroll
            for (int i = 0; i < 4; i++) {
                int gm = m0 + wr + fm * 16 + lg * 4 + i;
                unsigned short bv = f2bf(acc[fm][fn][i]);
                int b = gm >> 10, nseq = gm & 1023;
                if (gn < DIM_) {
                    int h = gn >> 6, d = gn & 63;
                    kb[(((size_t)(b * H_ + h) * N_) + nseq) * D_ + d] = bv;
                } else {
                    int c = gn - DIM_;
                    int h = c >> 6, d = c & 63;
                    vt[(((size_t)(b * H_ + h) * D_) + d) * N_ + nseq] = bv;
                }
            }
        }
}

// ---------------- flash attention, fixed-max softmax, 2 q-tiles per block ----------------
// SWAPPED QK^T: T = mfma(K, Q) puts lane's 4 score regs at 4 CONSECUTIVE j for one q,
// so pb loads become float4 and P-stores become ushort4 (8B). PV path unchanged.
__global__ __launch_bounds__(256) void attn_kernel(const unsigned short* __restrict__ kb,
                                                   const unsigned short* __restrict__ vt,
                                                   const float* __restrict__ pb,
                                                   const float* __restrict__ w_pos,
                                                   unsigned short* __restrict__ oh) {
    const int bh = blockIdx.x;   // 0..63  (b*8 + h)
    const int qp = blockIdx.y;   // 0..7   (pair of q-tiles)
    const int b = bh >> 3, h = bh & 7;
    __shared__ __align__(16) unsigned short Ks[64][72];
    __shared__ __align__(16) unsigned short Vs[64][72];     // Vs[d][j_local]
    __shared__ __align__(16) unsigned short Ps[4][16][72];  // per-wave P tile (reused A/B)
    const int t = threadIdx.x, w = t >> 6, l = t & 63, lr = l & 15, lg = l >> 4;

    float sw = 0.f;
    for (int p = 0; p < PD_; p++) sw += w_pos[p];
    const float alpha = sw * 0.044194173824159216f;  // 512^-0.5 * sum(w_pos); b_pos softmax-invariant

    const unsigned short* kh = kb + (size_t)bh * N_ * D_;
    const unsigned short* vh = vt + (size_t)bh * D_ * N_;
    const int q0 = qp * 128;
    const int sr = t >> 2, sk = (t & 3) * 8;

    // stage 128 Q rows through Ks (rows 0..63) and Vs (rows 64..127), hold in regs
    *reinterpret_cast<bf16x8*>(&Ks[sr][sk]) =
        *reinterpret_cast<const bf16x8*>(&kh[(size_t)(q0 + sr) * D_ + sk]);
    *reinterpret_cast<bf16x8*>(&Ks[sr][sk + 32]) =
        *reinterpret_cast<const bf16x8*>(&kh[(size_t)(q0 + sr) * D_ + sk + 32]);
    *reinterpret_cast<bf16x8*>(&Vs[sr][sk]) =
        *reinterpret_cast<const bf16x8*>(&kh[(size_t)(q0 + 64 + sr) * D_ + sk]);
    *reinterpret_cast<bf16x8*>(&Vs[sr][sk + 32]) =
        *reinterpret_cast<const bf16x8*>(&kh[(size_t)(q0 + 64 + sr) * D_ + sk + 32]);
    __syncthreads();
    const bf16x8 aqA0 = *reinterpret_cast<const bf16x8*>(&Ks[w * 16 + lr][lg * 8]);
    const bf16x8 aqA1 = *reinterpret_cast<const bf16x8*>(&Ks[w * 16 + lr][32 + lg * 8]);
    const bf16x8 aqB0 = *reinterpret_cast<const bf16x8*>(&Vs[w * 16 + lr][lg * 8]);
    const bf16x8 aqB1 = *reinterpret_cast<const bf16x8*>(&Vs[w * 16 + lr][32 + lg * 8]);
    __syncthreads();

    // prologue: stage K/V tile 0
    *reinterpret_cast<bf16x8*>(&Ks[sr][sk]) =
        *reinterpret_cast<const bf16x8*>(&kh[(size_t)sr * D_ + sk]);
    *reinterpret_cast<bf16x8*>(&Ks[sr][sk + 32]) =
        *reinterpret_cast<const bf16x8*>(&kh[(size_t)sr * D_ + sk + 32]);
    *reinterpret_cast<bf16x8*>(&Vs[sr][sk]) =
        *reinterpret_cast<const bf16x8*>(&vh[(size_t)sr * N_ + sk]);
    *reinterpret_cast<bf16x8*>(&Vs[sr][sk + 32]) =
        *reinterpret_cast<const bf16x8*>(&vh[(size_t)sr * N_ + sk + 32]);
    __syncthreads();

    // per-lane q rows (fixed): phase A -> q0 + w*16 + lr, phase B -> +64
    const float* pbrowA = pb + (size_t)(q0 + w * 16 + lr) * N_;
    const float* pbrowB = pb + (size_t)(q0 + 64 + w * 16 + lr) * N_;

    float lsumA = 0.f, lsumB = 0.f;
    f32x4 accA[4] = {}, accB[4] = {};

    for (int jt = 0; jt < 16; jt++) {
        const int j0 = jt * 64;

        // K fragments -> regs (shared by both q-tiles)
        bf16x8 bk[4][2];
#pragma unroll
        for (int fn = 0; fn < 4; fn++) {
            bk[fn][0] = *reinterpret_cast<const bf16x8*>(&Ks[fn * 16 + lr][lg * 8]);
            bk[fn][1] = *reinterpret_cast<const bf16x8*>(&Ks[fn * 16 + lr][32 + lg * 8]);
        }

        // issue next tile's global loads early (latency hides under compute)
        bf16x8 rk0, rk1, rv0, rv1;
        if (jt < 15) {
            const int jn = j0 + 64;
            rk0 = *reinterpret_cast<const bf16x8*>(&kh[(size_t)(jn + sr) * D_ + sk]);
            rk1 = *reinterpret_cast<const bf16x8*>(&kh[(size_t)(jn + sr) * D_ + sk + 32]);
            rv0 = *reinterpret_cast<const bf16x8*>(&vh[(size_t)sr * N_ + jn + sk]);
            rv1 = *reinterpret_cast<const bf16x8*>(&vh[(size_t)sr * N_ + jn + sk + 32]);
        }

        // T = K Q^T for both q-tiles: T[j][q], lane: q = lr, j = fn*16 + lg*4 + i
        f32x4 sA[4] = {}, sB[4] = {};
#pragma unroll
        for (int fn = 0; fn < 4; fn++) {
            sA[fn] = __builtin_amdgcn_mfma_f32_16x16x32_bf16(bk[fn][0], aqA0, sA[fn], 0, 0, 0);
            sA[fn] = __builtin_amdgcn_mfma_f32_16x16x32_bf16(bk[fn][1], aqA1, sA[fn], 0, 0, 0);
            sB[fn] = __builtin_amdgcn_mfma_f32_16x16x32_bf16(bk[fn][0], aqB0, sB[fn], 0, 0, 0);
            sB[fn] = __builtin_amdgcn_mfma_f32_16x16x32_bf16(bk[fn][1], aqB1, sB[fn], 0, 0, 0);
        }

        // V fragments -> regs (shared by both q-tiles)
        bf16x8 bv[4][2];
#pragma unroll
        for (int fd = 0; fd < 4; fd++) {
            bv[fd][0] = *reinterpret_cast<const bf16x8*>(&Vs[fd * 16 + lr][lg * 8]);
            bv[fd][1] = *reinterpret_cast<const bf16x8*>(&Vs[fd * 16 + lr][32 + lg * 8]);
        }

        // ---- phase A: softmax (vectorized pb/P) + PV for q-tile 0 ----
#pragma unroll
        for (int fn = 0; fn < 4; fn++) {
            float4 pv4 = *reinterpret_cast<const float4*>(&pbrowA[j0 + fn * 16 + lg * 4]);
            ushort4 ps;
            float p0 = __expf(sA[fn][0] * alpha + pv4.x); lsumA += p0; ps.x = f2bf(p0);
            float p1 = __expf(sA[fn][1] * alpha + pv4.y); lsumA += p1; ps.y = f2bf(p1);
            float p2 = __expf(sA[fn][2] * alpha + pv4.z); lsumA += p2; ps.z = f2bf(p2);
            float p3 = __expf(sA[fn][3] * alpha + pv4.w); lsumA += p3; ps.w = f2bf(p3);
            *reinterpret_cast<ushort4*>(&Ps[w][lr][fn * 16 + lg * 4]) = ps;
        }
        asm volatile("" ::: "memory");
        {
            bf16x8 pa0 = *reinterpret_cast<const bf16x8*>(&Ps[w][lr][lg * 8]);
            bf16x8 pa1 = *reinterpret_cast<const bf16x8*>(&Ps[w][lr][32 + lg * 8]);
#pragma unroll
            for (int fd = 0; fd < 4; fd++) {
                accA[fd] = __builtin_amdgcn_mfma_f32_16x16x32_bf16(pa0, bv[fd][0], accA[fd], 0, 0, 0);
                accA[fd] = __builtin_amdgcn_mfma_f32_16x16x32_bf16(pa1, bv[fd][1], accA[fd], 0, 0, 0);
            }
        }
        asm volatile("" ::: "memory");

        // ---- phase B: softmax + PV for q-tile 1 (Ps reused; in-wave DS order) ----
#pragma unroll
        for (int fn = 0; fn < 4; fn++) {
            float4 pv4 = *reinterpret_cast<const float4*>(&pbrowB[j0 + fn * 16 + lg * 4]);
            ushort4 ps;
            float p0 = __expf(sB[fn][0] * alpha + pv4.x); lsumB += p0; ps.x = f2bf(p0);
            float p1 = __expf(sB[fn][1] * alpha + pv4.y); lsumB += p1; ps.y = f2bf(p1);
            float p2 = __expf(sB[fn][2] * alpha + pv4.z); lsumB += p2; ps.z = f2bf(p2);
            float p3 = __expf(sB[fn][3] * alpha + pv4.w); lsumB += p3; ps.w = f2bf(p3);
            *reinterpret_cast<ushort4*>(&Ps[w][lr][fn * 16 + lg * 4]) = ps;
        }
        asm volatile("" ::: "memory");
        {
            bf16x8 pa0 = *reinterpret_cast<const bf16x8*>(&Ps[w][lr][lg * 8]);
            bf16x8 pa1 = *reinterpret_cast<const bf16x8*>(&Ps[w][lr][32 + lg * 8]);
#pragma unroll
            for (int fd = 0; fd < 4; fd++) {
                accB[fd] = __builtin_amdgcn_mfma_f32_16x16x32_bf16(pa0, bv[fd][0], accB[fd], 0, 0, 0);
                accB[fd] = __builtin_amdgcn_mfma_f32_16x16x32_bf16(pa1, bv[fd][1], accB[fd], 0, 0, 0);
            }
        }

        __syncthreads();   // all waves done with Ks/Vs tile jt
        if (jt < 15) {
            *reinterpret_cast<bf16x8*>(&Ks[sr][sk]) = rk0;
            *reinterpret_cast<bf16x8*>(&Ks[sr][sk + 32]) = rk1;
            *reinterpret_cast<bf16x8*>(&Vs[sr][sk]) = rv0;
            *reinterpret_cast<bf16x8*>(&Vs[sr][sk + 32]) = rv1;
        }
        __syncthreads();   // tile jt+1 visible
    }

    // reduce row sums across the 4 lane-groups (each lane's lsum is for q = lr)
    lsumA += __shfl_xor(lsumA, 16); lsumA += __shfl_xor(lsumA, 32);
    lsumB += __shfl_xor(lsumB, 16); lsumB += __shfl_xor(lsumB, 32);

    // epilogue rows are q = lg*4+i; gather those sums from lanes lg*4+i
    float invA[4], invB[4];
#pragma unroll
    for (int i = 0; i < 4; i++) {
        invA[i] = 1.f / __shfl(lsumA, lg * 4 + i);
        invB[i] = 1.f / __shfl(lsumB, lg * 4 + i);
    }

#pragma unroll
    for (int fd = 0; fd < 4; fd++) {
        int dcol = h * 64 + fd * 16 + lr;
#pragma unroll
        for (int i = 0; i < 4; i++) {
            int gqA = q0 + w * 16 + lg * 4 + i;
            oh[((size_t)(b * N_ + gqA)) * DIM_ + dcol] = f2bf(accA[fd][i] * invA[i]);
            int gqB = gqA + 64;
            oh[((size_t)(b * N_ + gqB)) * DIM_ + dcol] = f2bf(accB[fd][i] * invB[i]);
        }
    }
}

// ---------------- final = oh @ W_out^T + b_out -> FLOAT32 d_out, 128x64 tile, BK=64 ----------------
__global__ __launch_bounds__(256) void out_gemm(const unsigned short* __restrict__ ohb,
                                                const unsigned short* __restrict__ wob,
                                                const float* __restrict__ b_out,
                                                float* __restrict__ out) {
    __shared__ __align__(16) unsigned short As[128][72];
    __shared__ __align__(16) unsigned short Bs[64][72];
    const int m0 = blockIdx.x * 128;
    const int n0 = blockIdx.y * 64;
    const int t = threadIdx.x;
    const int w = t >> 6, l = t & 63;
    const int wr = (w >> 1) * 64, wc = (w & 1) * 32;
    const int lr = l & 15, lg = l >> 4;
    const int ar = t >> 1, ac = (t & 1) * 32;
    const int br = t >> 2, bc = (t & 3) * 16;

    f32x4 acc[4][2] = {};

    for (int k0 = 0; k0 < DIM_; k0 += 64) {
        __syncthreads();
#pragma unroll
        for (int u = 0; u < 4; u++)
            *reinterpret_cast<bf16x8*>(&As[ar][ac + u * 8]) =
                *reinterpret_cast<const bf16x8*>(&ohb[(size_t)(m0 + ar) * DIM_ + k0 + ac + u * 8]);
#pragma unroll
        for (int u = 0; u < 2; u++)
            *reinterpret_cast<bf16x8*>(&Bs[br][bc + u * 8]) =
                *reinterpret_cast<const bf16x8*>(&wob[(size_t)(n0 + br) * DIM_ + k0 + bc + u * 8]);
        __syncthreads();
#pragma unroll
        for (int kh = 0; kh < 2; kh++) {
            bf16x8 b0 = *reinterpret_cast<const bf16x8*>(&Bs[wc + lr][kh * 32 + lg * 8]);
            bf16x8 b1 = *reinterpret_cast<const bf16x8*>(&Bs[wc + 16 + lr][kh * 32 + lg * 8]);
#pragma unroll
            for (int fm = 0; fm < 4; fm++) {
                bf16x8 a = *reinterpret_cast<const bf16x8*>(&As[wr + fm * 16 + lr][kh * 32 + lg * 8]);
                acc[fm][0] = __builtin_amdgcn_mfma_f32_16x16x32_bf16(a, b0, acc[fm][0], 0, 0, 0);
                acc[fm][1] = __builtin_amdgcn_mfma_f32_16x16x32_bf16(a, b1, acc[fm][1], 0, 0, 0);
            }
        }
    }

#pragma unroll
    for (int fm = 0; fm < 4; fm++)
#pragma unroll
        for (int fn = 0; fn < 2; fn++) {
            int gn = n0 + wc + fn * 16 + lr;
            float bias = b_out[gn];
#pragma unroll
            for (int i = 0; i < 4; i++) {
                int gm = m0 + wr + fm * 16 + lg * 4 + i;
                out[(size_t)gm * DIM_ + gn] = acc[fm][fn][i] + bias;
            }
        }
}

extern "C" void kernel_launch(void* const* d_in, const int* in_sizes, int n_in,
                              void* d_out, int out_size, void* d_ws, size_t ws_size,
                              hipStream_t stream) {
    const float* x     = (const float*)d_in[0];
    const float* pos   = (const float*)d_in[1];
    const float* W_kv  = (const float*)d_in[2];
    const float* W_out = (const float*)d_in[3];
    const float* b_out = (const float*)d_in[4];
    const float* w_pos = (const float*)d_in[5];
    // d_in[6] = b_pos: scalar added to every score -> softmax-invariant -> unused.

    char* ws = (char*)d_ws;
    unsigned short* xb   = (unsigned short*)(ws);               // 8 MB   x in bf16
    unsigned short* wkv  = (unsigned short*)(ws + 8388608);     // 1 MB   W_kv bf16
    unsigned short* wout = (unsigned short*)(ws + 9437184);     // 0.5 MB W_out bf16
    unsigned short* kb   = (unsigned short*)(ws + 9961472);     // 8 MB   k[b][h][n][d]
    unsigned short* vt   = (unsigned short*)(ws + 18350080);    // 8 MB   v^T[b][h][d][n]
    float*          pb   = (float*)(ws + 26738688);             // 4 MB   pos_bias fp32
    unsigned short* oh   = (unsigned short*)(ws + 30932992);    // 8 MB   attn out (b,n,h*d)
    float*          out  = (float*)d_out;                       // FLOAT32 output

    cast_all<<<4864, 256, 0, stream>>>(x, W_kv, W_out, xb, wkv, wout);
    pos_bias_kernel<<<4096, 256, 0, stream>>>(pos, w_pos, pb);
    kv_gemm<<<dim3(64, 16), 256, 0, stream>>>(xb, wkv, kb, vt);
    attn_kernel<<<dim3(64, 8), 256, 0, stream>>>(kb, vt, pb, w_pos, oh);
    out_gemm<<<dim3(64, 8), 256, 0, stream>>>(oh, wout, b_out, out);
}

// Round 15
// 120.293 us; speedup vs baseline: 1.0370x; 1.0370x over previous
//
#include <hip/hip_runtime.h>

#define B_ 8
#define N_ 1024
#define DIM_ 512
#define H_ 8
#define D_ 64
#define PD_ 50
#define PBROWS 256

typedef __attribute__((ext_vector_type(4))) float f32x4;
typedef __attribute__((ext_vector_type(8))) __bf16 bf16x8;

__device__ __forceinline__ unsigned short f2bf(float f) {
    unsigned int u = __float_as_uint(f);
    u += 0x7FFFu + ((u >> 16) & 1u);   // round-to-nearest-even
    return (unsigned short)(u >> 16);
}

// ---------------- fp32 -> bf16 cast: x, W_kv, W_out in ONE launch ----------------
__global__ __launch_bounds__(256) void cast_all(const float* __restrict__ x,
                                                const float* __restrict__ wkv,
                                                const float* __restrict__ wout,
                                                unsigned short* __restrict__ xb,
                                                unsigned short* __restrict__ wkvb,
                                                unsigned short* __restrict__ woutb) {
    const int bid = blockIdx.x;
    const float* src;
    unsigned short* dst;
    int idx;
    if (bid < 4096)      { src = x;    dst = xb;    idx = bid; }
    else if (bid < 4608) { src = wkv;  dst = wkvb;  idx = bid - 4096; }
    else                 { src = wout; dst = woutb; idx = bid - 4608; }
    int i = idx * 256 + threadIdx.x;
    float4 v = reinterpret_cast<const float4*>(src)[i];
    ushort4 o;
    o.x = f2bf(v.x); o.y = f2bf(v.y); o.z = f2bf(v.z); o.w = f2bf(v.w);
    reinterpret_cast<ushort4*>(dst)[i] = o;
}

// ---------------- pos_bias: LDS-staged, coalesced float4 global loads ----------------
__global__ __launch_bounds__(256) void pos_bias_kernel(const float* __restrict__ pos,
                                                       const float* __restrict__ w_pos,
                                                       float* __restrict__ pb) {
    __shared__ float buf[PBROWS * PD_];   // 51.2 KB
    const int t = threadIdx.x;
    const size_t base = (size_t)blockIdx.x * (PBROWS * PD_);
    const float4* src = reinterpret_cast<const float4*>(pos + base);
    float4* dst = reinterpret_cast<float4*>(buf);
#pragma unroll 4
    for (int i = t; i < PBROWS * PD_ / 4; i += 256)
        dst[i] = src[i];
    __syncthreads();
    float acc = 0.f;
    const float* row = buf + t * PD_;
#pragma unroll
    for (int p = 0; p < PD_; p++) acc += row[p] * w_pos[p];
    pb[(size_t)blockIdx.x * PBROWS + t] = acc;
}

// ---------------- kv = x @ W_kv^T, 128x64 tile, BK=64, scatter k->kb, v->vt ----------------
__global__ __launch_bounds__(256) void kv_gemm(const unsigned short* __restrict__ xb,
                                               const unsigned short* __restrict__ wb,
                                               unsigned short* __restrict__ kb,
                                               unsigned short* __restrict__ vt) {
    __shared__ __align__(16) unsigned short As[128][72];   // +8 pad
    __shared__ __align__(16) unsigned short Bs[64][72];
    const int m0 = blockIdx.x * 128;
    const int n0 = blockIdx.y * 64;
    const int t = threadIdx.x;
    const int w = t >> 6, l = t & 63;
    const int wr = (w >> 1) * 64, wc = (w & 1) * 32;
    const int lr = l & 15, lg = l >> 4;
    const int ar = t >> 1, ac = (t & 1) * 32;          // A: 4 x bf16x8 per thread
    const int br = t >> 2, bc = (t & 3) * 16;          // B: 2 x bf16x8 per thread

    f32x4 acc[4][2] = {};

    for (int k0 = 0; k0 < DIM_; k0 += 64) {
        __syncthreads();
#pragma unroll
        for (int u = 0; u < 4; u++)
            *reinterpret_cast<bf16x8*>(&As[ar][ac + u * 8]) =
                *reinterpret_cast<const bf16x8*>(&xb[(size_t)(m0 + ar) * DIM_ + k0 + ac + u * 8]);
#pragma unroll
        for (int u = 0; u < 2; u++)
            *reinterpret_cast<bf16x8*>(&Bs[br][bc + u * 8]) =
                *reinterpret_cast<const bf16x8*>(&wb[(size_t)(n0 + br) * DIM_ + k0 + bc + u * 8]);
        __syncthreads();
#pragma unroll
        for (int kh = 0; kh < 2; kh++) {
            bf16x8 b0 = *reinterpret_cast<const bf16x8*>(&Bs[wc + lr][kh * 32 + lg * 8]);
            bf16x8 b1 = *reinterpret_cast<const bf16x8*>(&Bs[wc + 16 + lr][kh * 32 + lg * 8]);
#pragma unroll
            for (int fm = 0; fm < 4; fm++) {
                bf16x8 a = *reinterpret_cast<const bf16x8*>(&As[wr + fm * 16 + lr][kh * 32 + lg * 8]);
                acc[fm][0] = __builtin_amdgcn_mfma_f32_16x16x32_bf16(a, b0, acc[fm][0], 0, 0, 0);
                acc[fm][1] = __builtin_amdgcn_mfma_f32_16x16x32_bf16(a, b1, acc[fm][1], 0, 0, 0);
            }
        }
    }

#pragma unroll
    for (int fm = 0; fm < 4; fm++)
#pragma unroll
        for (int fn = 0; fn < 2; fn++) {
            int gn = n0 + wc + fn * 16 + lr;
#pragma unroll
            for (int i = 0; i < 4; i++) {
                int gm = m0 + wr + fm * 16 + lg * 4 + i;
                unsigned short bv = f2bf(acc[fm][fn][i]);
                int b = gm >> 10, nseq = gm & 1023;
                if (gn < DIM_) {
                    int h = gn >> 6, d = gn & 63;
                    kb[(((size_t)(b * H_ + h) * N_) + nseq) * D_ + d] = bv;
                } else {
                    int c = gn - DIM_;
                    int h = c >> 6, d = c & 63;
                    vt[(((size_t)(b * H_ + h) * D_) + d) * N_ + nseq] = bv;
                }
            }
        }
}

// ---------------- flash attention, fixed-max softmax, 2 q-tiles per block ----------------
// K/V fragments register-held per jt, shared by both q-tiles (halves LDS reads/work);
// next-tile K/V global loads issued pre-compute, LDS-written post-barrier (T14).
__global__ __launch_bounds__(256) void attn_kernel(const unsigned short* __restrict__ kb,
                                                   const unsigned short* __restrict__ vt,
                                                   const float* __restrict__ pb,
                                                   const float* __restrict__ w_pos,
                                                   unsigned short* __restrict__ oh) {
    const int bh = blockIdx.x;   // 0..63  (b*8 + h)
    const int qp = blockIdx.y;   // 0..7   (pair of q-tiles)
    const int b = bh >> 3, h = bh & 7;
    __shared__ __align__(16) unsigned short Ks[64][72];
    __shared__ __align__(16) unsigned short Vs[64][72];     // Vs[d][j_local]
    __shared__ __align__(16) unsigned short Ps[4][16][72];  // per-wave P tile (reused A/B)
    const int t = threadIdx.x, w = t >> 6, l = t & 63, lr = l & 15, lg = l >> 4;

    float sw = 0.f;
    for (int p = 0; p < PD_; p++) sw += w_pos[p];
    const float alpha = sw * 0.044194173824159216f;  // 512^-0.5 * sum(w_pos); b_pos softmax-invariant

    const unsigned short* kh = kb + (size_t)bh * N_ * D_;
    const unsigned short* vh = vt + (size_t)bh * D_ * N_;
    const int q0 = qp * 128;
    const int sr = t >> 2, sk = (t & 3) * 8;

    // stage 128 Q rows through Ks (rows 0..63) and Vs (rows 64..127), hold in regs
    *reinterpret_cast<bf16x8*>(&Ks[sr][sk]) =
        *reinterpret_cast<const bf16x8*>(&kh[(size_t)(q0 + sr) * D_ + sk]);
    *reinterpret_cast<bf16x8*>(&Ks[sr][sk + 32]) =
        *reinterpret_cast<const bf16x8*>(&kh[(size_t)(q0 + sr) * D_ + sk + 32]);
    *reinterpret_cast<bf16x8*>(&Vs[sr][sk]) =
        *reinterpret_cast<const bf16x8*>(&kh[(size_t)(q0 + 64 + sr) * D_ + sk]);
    *reinterpret_cast<bf16x8*>(&Vs[sr][sk + 32]) =
        *reinterpret_cast<const bf16x8*>(&kh[(size_t)(q0 + 64 + sr) * D_ + sk + 32]);
    __syncthreads();
    const bf16x8 aqA0 = *reinterpret_cast<const bf16x8*>(&Ks[w * 16 + lr][lg * 8]);
    const bf16x8 aqA1 = *reinterpret_cast<const bf16x8*>(&Ks[w * 16 + lr][32 + lg * 8]);
    const bf16x8 aqB0 = *reinterpret_cast<const bf16x8*>(&Vs[w * 16 + lr][lg * 8]);
    const bf16x8 aqB1 = *reinterpret_cast<const bf16x8*>(&Vs[w * 16 + lr][32 + lg * 8]);
    __syncthreads();

    // prologue: stage K/V tile 0
    *reinterpret_cast<bf16x8*>(&Ks[sr][sk]) =
        *reinterpret_cast<const bf16x8*>(&kh[(size_t)sr * D_ + sk]);
    *reinterpret_cast<bf16x8*>(&Ks[sr][sk + 32]) =
        *reinterpret_cast<const bf16x8*>(&kh[(size_t)sr * D_ + sk + 32]);
    *reinterpret_cast<bf16x8*>(&Vs[sr][sk]) =
        *reinterpret_cast<const bf16x8*>(&vh[(size_t)sr * N_ + sk]);
    *reinterpret_cast<bf16x8*>(&Vs[sr][sk + 32]) =
        *reinterpret_cast<const bf16x8*>(&vh[(size_t)sr * N_ + sk + 32]);
    __syncthreads();

    float lA[4] = {0.f, 0.f, 0.f, 0.f}, lB[4] = {0.f, 0.f, 0.f, 0.f};
    f32x4 accA[4] = {}, accB[4] = {};

    for (int jt = 0; jt < 16; jt++) {
        const int j0 = jt * 64;

        // K fragments -> regs (shared by both q-tiles)
        bf16x8 bk[4][2];
#pragma unroll
        for (int fn = 0; fn < 4; fn++) {
            bk[fn][0] = *reinterpret_cast<const bf16x8*>(&Ks[fn * 16 + lr][lg * 8]);
            bk[fn][1] = *reinterpret_cast<const bf16x8*>(&Ks[fn * 16 + lr][32 + lg * 8]);
        }

        // issue next tile's global loads early (latency hides under compute)
        bf16x8 rk0, rk1, rv0, rv1;
        if (jt < 15) {
            const int jn = j0 + 64;
            rk0 = *reinterpret_cast<const bf16x8*>(&kh[(size_t)(jn + sr) * D_ + sk]);
            rk1 = *reinterpret_cast<const bf16x8*>(&kh[(size_t)(jn + sr) * D_ + sk + 32]);
            rv0 = *reinterpret_cast<const bf16x8*>(&vh[(size_t)sr * N_ + jn + sk]);
            rv1 = *reinterpret_cast<const bf16x8*>(&vh[(size_t)sr * N_ + jn + sk + 32]);
        }

        // QK^T for both q-tiles
        f32x4 sA[4] = {}, sB[4] = {};
#pragma unroll
        for (int fn = 0; fn < 4; fn++) {
            sA[fn] = __builtin_amdgcn_mfma_f32_16x16x32_bf16(aqA0, bk[fn][0], sA[fn], 0, 0, 0);
            sA[fn] = __builtin_amdgcn_mfma_f32_16x16x32_bf16(aqA1, bk[fn][1], sA[fn], 0, 0, 0);
            sB[fn] = __builtin_amdgcn_mfma_f32_16x16x32_bf16(aqB0, bk[fn][0], sB[fn], 0, 0, 0);
            sB[fn] = __builtin_amdgcn_mfma_f32_16x16x32_bf16(aqB1, bk[fn][1], sB[fn], 0, 0, 0);
        }

        // V fragments -> regs (shared by both q-tiles)
        bf16x8 bv[4][2];
#pragma unroll
        for (int fd = 0; fd < 4; fd++) {
            bv[fd][0] = *reinterpret_cast<const bf16x8*>(&Vs[fd * 16 + lr][lg * 8]);
            bv[fd][1] = *reinterpret_cast<const bf16x8*>(&Vs[fd * 16 + lr][32 + lg * 8]);
        }

        // ---- phase A: softmax + PV for q-tile 0 ----
#pragma unroll
        for (int fn = 0; fn < 4; fn++) {
            int gj = j0 + fn * 16 + lr;
#pragma unroll
            for (int i = 0; i < 4; i++) {
                int gq = q0 + w * 16 + lg * 4 + i;
                float p = __expf(sA[fn][i] * alpha + pb[(size_t)gq * N_ + gj]);
                lA[i] += p;
                Ps[w][lg * 4 + i][fn * 16 + lr] = f2bf(p);
            }
        }
        asm volatile("" ::: "memory");
        {
            bf16x8 pa0 = *reinterpret_cast<const bf16x8*>(&Ps[w][lr][lg * 8]);
            bf16x8 pa1 = *reinterpret_cast<const bf16x8*>(&Ps[w][lr][32 + lg * 8]);
#pragma unroll
            for (int fd = 0; fd < 4; fd++) {
                accA[fd] = __builtin_amdgcn_mfma_f32_16x16x32_bf16(pa0, bv[fd][0], accA[fd], 0, 0, 0);
                accA[fd] = __builtin_amdgcn_mfma_f32_16x16x32_bf16(pa1, bv[fd][1], accA[fd], 0, 0, 0);
            }
        }
        asm volatile("" ::: "memory");

        // ---- phase B: softmax + PV for q-tile 1 (Ps reused; in-wave DS order) ----
#pragma unroll
        for (int fn = 0; fn < 4; fn++) {
            int gj = j0 + fn * 16 + lr;
#pragma unroll
            for (int i = 0; i < 4; i++) {
                int gq = q0 + 64 + w * 16 + lg * 4 + i;
                float p = __expf(sB[fn][i] * alpha + pb[(size_t)gq * N_ + gj]);
                lB[i] += p;
                Ps[w][lg * 4 + i][fn * 16 + lr] = f2bf(p);
            }
        }
        asm volatile("" ::: "memory");
        {
            bf16x8 pa0 = *reinterpret_cast<const bf16x8*>(&Ps[w][lr][lg * 8]);
            bf16x8 pa1 = *reinterpret_cast<const bf16x8*>(&Ps[w][lr][32 + lg * 8]);
#pragma unroll
            for (int fd = 0; fd < 4; fd++) {
                accB[fd] = __builtin_amdgcn_mfma_f32_16x16x32_bf16(pa0, bv[fd][0], accB[fd], 0, 0, 0);
                accB[fd] = __builtin_amdgcn_mfma_f32_16x16x32_bf16(pa1, bv[fd][1], accB[fd], 0, 0, 0);
            }
        }

        __syncthreads();   // all waves done with Ks/Vs tile jt
        if (jt < 15) {
            *reinterpret_cast<bf16x8*>(&Ks[sr][sk]) = rk0;
            *reinterpret_cast<bf16x8*>(&Ks[sr][sk + 32]) = rk1;
            *reinterpret_cast<bf16x8*>(&Vs[sr][sk]) = rv0;
            *reinterpret_cast<bf16x8*>(&Vs[sr][sk + 32]) = rv1;
        }
        __syncthreads();   // tile jt+1 visible
    }

    // one-time row-sum reduces
#pragma unroll
    for (int msk = 1; msk < 16; msk <<= 1)
#pragma unroll
        for (int i = 0; i < 4; i++) {
            lA[i] += __shfl_xor(lA[i], msk);
            lB[i] += __shfl_xor(lB[i], msk);
        }

#pragma unroll
    for (int fd = 0; fd < 4; fd++) {
        int dcol = h * 64 + fd * 16 + lr;
#pragma unroll
        for (int i = 0; i < 4; i++) {
            int gqA = q0 + w * 16 + lg * 4 + i;
            oh[((size_t)(b * N_ + gqA)) * DIM_ + dcol] = f2bf(accA[fd][i] / lA[i]);
            int gqB = gqA + 64;
            oh[((size_t)(b * N_ + gqB)) * DIM_ + dcol] = f2bf(accB[fd][i] / lB[i]);
        }
    }
}

// ---------------- final = oh @ W_out^T + b_out -> FLOAT32 d_out, 128x64 tile, BK=64 ----------------
__global__ __launch_bounds__(256) void out_gemm(const unsigned short* __restrict__ ohb,
                                                const unsigned short* __restrict__ wob,
                                                const float* __restrict__ b_out,
                                                float* __restrict__ out) {
    __shared__ __align__(16) unsigned short As[128][72];
    __shared__ __align__(16) unsigned short Bs[64][72];
    const int m0 = blockIdx.x * 128;
    const int n0 = blockIdx.y * 64;
    const int t = threadIdx.x;
    const int w = t >> 6, l = t & 63;
    const int wr = (w >> 1) * 64, wc = (w & 1) * 32;
    const int lr = l & 15, lg = l >> 4;
    const int ar = t >> 1, ac = (t & 1) * 32;
    const int br = t >> 2, bc = (t & 3) * 16;

    f32x4 acc[4][2] = {};

    for (int k0 = 0; k0 < DIM_; k0 += 64) {
        __syncthreads();
#pragma unroll
        for (int u = 0; u < 4; u++)
            *reinterpret_cast<bf16x8*>(&As[ar][ac + u * 8]) =
                *reinterpret_cast<const bf16x8*>(&ohb[(size_t)(m0 + ar) * DIM_ + k0 + ac + u * 8]);
#pragma unroll
        for (int u = 0; u < 2; u++)
            *reinterpret_cast<bf16x8*>(&Bs[br][bc + u * 8]) =
                *reinterpret_cast<const bf16x8*>(&wob[(size_t)(n0 + br) * DIM_ + k0 + bc + u * 8]);
        __syncthreads();
#pragma unroll
        for (int kh = 0; kh < 2; kh++) {
            bf16x8 b0 = *reinterpret_cast<const bf16x8*>(&Bs[wc + lr][kh * 32 + lg * 8]);
            bf16x8 b1 = *reinterpret_cast<const bf16x8*>(&Bs[wc + 16 + lr][kh * 32 + lg * 8]);
#pragma unroll
            for (int fm = 0; fm < 4; fm++) {
                bf16x8 a = *reinterpret_cast<const bf16x8*>(&As[wr + fm * 16 + lr][kh * 32 + lg * 8]);
                acc[fm][0] = __builtin_amdgcn_mfma_f32_16x16x32_bf16(a, b0, acc[fm][0], 0, 0, 0);
                acc[fm][1] = __builtin_amdgcn_mfma_f32_16x16x32_bf16(a, b1, acc[fm][1], 0, 0, 0);
            }
        }
    }

#pragma unroll
    for (int fm = 0; fm < 4; fm++)
#pragma unroll
        for (int fn = 0; fn < 2; fn++) {
            int gn = n0 + wc + fn * 16 + lr;
            float bias = b_out[gn];
#pragma unroll
            for (int i = 0; i < 4; i++) {
                int gm = m0 + wr + fm * 16 + lg * 4 + i;
                out[(size_t)gm * DIM_ + gn] = acc[fm][fn][i] + bias;
            }
        }
}

extern "C" void kernel_launch(void* const* d_in, const int* in_sizes, int n_in,
                              void* d_out, int out_size, void* d_ws, size_t ws_size,
                              hipStream_t stream) {
    const float* x     = (const float*)d_in[0];
    const float* pos   = (const float*)d_in[1];
    const float* W_kv  = (const float*)d_in[2];
    const float* W_out = (const float*)d_in[3];
    const float* b_out = (const float*)d_in[4];
    const float* w_pos = (const float*)d_in[5];
    // d_in[6] = b_pos: scalar added to every score -> softmax-invariant -> unused.

    char* ws = (char*)d_ws;
    unsigned short* xb   = (unsigned short*)(ws);               // 8 MB   x in bf16
    unsigned short* wkv  = (unsigned short*)(ws + 8388608);     // 1 MB   W_kv bf16
    unsigned short* wout = (unsigned short*)(ws + 9437184);     // 0.5 MB W_out bf16
    unsigned short* kb   = (unsigned short*)(ws + 9961472);     // 8 MB   k[b][h][n][d]
    unsigned short* vt   = (unsigned short*)(ws + 18350080);    // 8 MB   v^T[b][h][d][n]
    float*          pb   = (float*)(ws + 26738688);             // 4 MB   pos_bias fp32
    unsigned short* oh   = (unsigned short*)(ws + 30932992);    // 8 MB   attn out (b,n,h*d)
    float*          out  = (float*)d_out;                       // FLOAT32 output

    cast_all<<<4864, 256, 0, stream>>>(x, W_kv, W_out, xb, wkv, wout);
    pos_bias_kernel<<<4096, 256, 0, stream>>>(pos, w_pos, pb);
    kv_gemm<<<dim3(64, 16), 256, 0, stream>>>(xb, wkv, kb, vt);
    attn_kernel<<<dim3(64, 8), 256, 0, stream>>>(kb, vt, pb, w_pos, oh);
    out_gemm<<<dim3(64, 8), 256, 0, stream>>>(oh, wout, b_out, out);
}